// Round 6
// baseline (309.211 us; speedup 1.0000x reference)
//
#include <hip/hip_runtime.h>
#include <hip/hip_bf16.h>

#define BB 8
#define CC 256
#define NN 4096
#define KP 64   // projection dim K = C/4
#define LOG2E 1.44269504088896f

typedef _Float16 f16x8 __attribute__((ext_vector_type(8)));
typedef _Float16 f16x4 __attribute__((ext_vector_type(4)));
typedef float    f32x4 __attribute__((ext_vector_type(4)));

#define MFMA16(a, b, c) __builtin_amdgcn_mfma_f32_16x16x32_f16((a), (b), (c), 0, 0, 0)

__device__ __forceinline__ float fast_exp2(float x) {
#if __has_builtin(__builtin_amdgcn_exp2f)
    return __builtin_amdgcn_exp2f(x);
#else
    return __expf(x * 0.69314718055994531f);
#endif
}

// 16-lane (DPP-row) rotate reductions: VALU-speed, off the LDS pipe
template<int CTRL>
__device__ __forceinline__ float dpp_ror_f(float x) {
    return __int_as_float(__builtin_amdgcn_update_dpp(
        0, __float_as_int(x), CTRL, 0xF, 0xF, true));
}
__device__ __forceinline__ float max16(float x) {
    x = fmaxf(x, dpp_ror_f<0x128>(x));
    x = fmaxf(x, dpp_ror_f<0x124>(x));
    x = fmaxf(x, dpp_ror_f<0x122>(x));
    x = fmaxf(x, dpp_ror_f<0x121>(x));
    return x;
}
__device__ __forceinline__ float sum16(float x) {
    x += dpp_ror_f<0x128>(x);
    x += dpp_ror_f<0x124>(x);
    x += dpp_ror_f<0x122>(x);
    x += dpp_ror_f<0x121>(x);
    return x;
}

// ---------------------------------------------------------------------------
// Kernel 0: WF|WG|WH fp32 -> concatenated fp16 W16[384][256].
// ---------------------------------------------------------------------------
__global__ __launch_bounds__(256) void wconv_kernel(
    const float* __restrict__ WF, const float* __restrict__ WG,
    const float* __restrict__ WH, _Float16* __restrict__ W16)
{
    int gid = blockIdx.x * 256 + threadIdx.x;
    int i4  = gid * 4;
    const float* src;
    if (i4 < 64 * CC)        src = WF + i4;
    else if (i4 < 128 * CC)  src = WG + (i4 - 64 * CC);
    else                     src = WH + (i4 - 128 * CC);
    float4 v = *(const float4*)src;
    f16x4 o = { (_Float16)v.x, (_Float16)v.y, (_Float16)v.z, (_Float16)v.w };
    *(f16x4*)(W16 + i4) = o;
}

// ---------------------------------------------------------------------------
// Kernel 1: fp16 MFMA projection, 64-token tiles.
// g pre-scaled by log2e. hT transposed+permuted per 64-block:
//   col = (tok&~63) + (tok&15)*4 + ((tok>>4)&3).
// Feat loads batched (8 outstanding) before LDS conversion.
// ---------------------------------------------------------------------------
__global__ __launch_bounds__(256, 3) void proj16_kernel(
    const float* __restrict__ feat, const _Float16* __restrict__ W16,
    _Float16* __restrict__ fb, _Float16* __restrict__ gb,
    _Float16* __restrict__ hT)
{
    __shared__ __align__(16) _Float16 ft[64][264];
    const int b = blockIdx.y, n0 = blockIdx.x * 64, t = threadIdx.x;

    // stage feat[b][:, n0..n0+63] -> ft[tok][c] fp16; two 8-load batches
    #pragma unroll
    for (int half = 0; half < 2; half++) {
        float4 tmp[8];
        #pragma unroll
        for (int i = 0; i < 8; i++) {
            int v = t + (half * 8 + i) * 256;
            int c = v >> 4, nq = v & 15;
            tmp[i] = *(const float4*)(feat + ((size_t)b * CC + c) * NN + n0 + nq * 4);
        }
        #pragma unroll
        for (int i = 0; i < 8; i++) {
            int v = t + (half * 8 + i) * 256;
            int c = v >> 4, nq = v & 15;
            ft[nq * 4 + 0][c] = (_Float16)tmp[i].x;
            ft[nq * 4 + 1][c] = (_Float16)tmp[i].y;
            ft[nq * 4 + 2][c] = (_Float16)tmp[i].z;
            ft[nq * 4 + 3][c] = (_Float16)tmp[i].w;
        }
    }
    __syncthreads();

    const int w = t >> 6, lane = t & 63, quad = lane >> 4, ln = lane & 15;
    const int rowbase = w * 96;

    f32x4 acc[6][4] = {};
    #pragma unroll
    for (int ks = 0; ks < 8; ks++) {
        const int c0 = ks * 32;
        f16x8 bfr[4];
        #pragma unroll
        for (int tf = 0; tf < 4; tf++)
            bfr[tf] = *(const f16x8*)&ft[tf * 16 + ln][c0 + quad * 8];
        #pragma unroll
        for (int af = 0; af < 6; af++) {
            f16x8 a = *(const f16x8*)(W16 + (size_t)(rowbase + af * 16 + ln) * CC + c0 + quad * 8);
            #pragma unroll
            for (int tf = 0; tf < 4; tf++)
                acc[af][tf] = MFMA16(a, bfr[tf], acc[af][tf]);
        }
    }

    // C/D layout: col(tok)=ln, row(out)=quad*4+r
    #pragma unroll
    for (int af = 0; af < 6; af++) {
        const int orow0 = rowbase + af * 16 + quad * 4;   // wave-uniform range
        if (orow0 < 64) {
            #pragma unroll
            for (int tf = 0; tf < 4; tf++) {
                const int tok = n0 + tf * 16 + ln;
                f16x4 pk = { (_Float16)acc[af][tf][0], (_Float16)acc[af][tf][1],
                             (_Float16)acc[af][tf][2], (_Float16)acc[af][tf][3] };
                *(f16x4*)(fb + ((size_t)b * NN + tok) * KP + orow0) = pk;
            }
        } else if (orow0 < 128) {
            #pragma unroll
            for (int tf = 0; tf < 4; tf++) {
                const int tok = n0 + tf * 16 + ln;
                f16x4 pk = { (_Float16)(acc[af][tf][0] * LOG2E),
                             (_Float16)(acc[af][tf][1] * LOG2E),
                             (_Float16)(acc[af][tf][2] * LOG2E),
                             (_Float16)(acc[af][tf][3] * LOG2E) };
                *(f16x4*)(gb + ((size_t)b * NN + tok) * KP + (orow0 - 64)) = pk;
            }
        } else {
            #pragma unroll
            for (int r = 0; r < 4; r++) {
                const int d = orow0 - 128 + r;
                f16x4 pk = { (_Float16)acc[af][0][r], (_Float16)acc[af][1][r],
                             (_Float16)acc[af][2][r], (_Float16)acc[af][3][r] };
                *(f16x4*)(hT + ((size_t)b * CC + d) * NN + n0 + ln * 4) = pk;
            }
        }
    }
}

// ---------------------------------------------------------------------------
// Kernel 2: fp16 MFMA flash attention, Tq=64, Tm=128, 4 symmetric waves.
// 32 iterations (vs 64): halved barrier+softmax fixed costs.
// Q A-frags loaded once from global (no g_s). f_s stride 66 / p_s stride 130
// (odd dword strides -> <=4-way LDS conflicts on b128 reads).
// ---------------------------------------------------------------------------
__global__ __launch_bounds__(256, 2) void attn16_kernel(
    const _Float16* __restrict__ fb, const _Float16* __restrict__ gb,
    const _Float16* __restrict__ hT, const float* __restrict__ inp,
    const float* __restrict__ gamma, float* __restrict__ out)
{
    __shared__ __align__(16) _Float16 f_s[128][66];   // 16.9 KB
    __shared__ __align__(16) _Float16 p_s[64][130];   // 16.6 KB
    __shared__ float alpha_s[64];
    __shared__ float l_s[64];

    const int b = blockIdx.x, q0 = blockIdx.y * 64, t = threadIdx.x;
    const int w = t >> 6, lane = t & 63, quad = lane >> 4, ln = lane & 15;
    const int dbase = w * 64;
    const int srow = t & 127, scol = (t >> 7) * 32;   // f staging assignment

    // loop-invariant Q A-frags straight from global (L2-resident)
    const _Float16* gsrc = gb + ((size_t)b * NN + q0 + w * 16 + ln) * KP + quad * 8;
    f16x8 ag0 = *(const f16x8*)(gsrc);
    f16x8 ag1 = *(const f16x8*)(gsrc + 32);

    // preload f tile 0 (4 x 16B per thread: row srow, cols scol..scol+31)
    f16x8 fr[4];
    {
        const _Float16* src = fb + ((size_t)b * NN + srow) * KP + scol;
        fr[0] = *(const f16x8*)(src);
        fr[1] = *(const f16x8*)(src + 8);
        fr[2] = *(const f16x8*)(src + 16);
        fr[3] = *(const f16x8*)(src + 24);
    }

    float m_run[4] = {-1e30f, -1e30f, -1e30f, -1e30f};
    float l_run[4] = {0.f, 0.f, 0.f, 0.f};
    f32x4 acc[4][4] = {};

    #pragma unroll 1
    for (int mt = 0; mt < NN / 128; mt++) {
        const int m0 = mt * 128;

        // current f tile regs -> LDS
        *(f16x8*)&f_s[srow][scol]      = fr[0];
        *(f16x8*)&f_s[srow][scol + 8]  = fr[1];
        *(f16x8*)&f_s[srow][scol + 16] = fr[2];
        *(f16x8*)&f_s[srow][scol + 24] = fr[3];
        __syncthreads();   // barrier 1: f_s ready

        // prefetch next f tile + this tile's hv (drain covered by QK+softmax)
        {
            const int m0n = ((mt + 1) & 31) * 128;   // wrap: harmless reload
            const _Float16* src = fb + ((size_t)b * NN + m0n + srow) * KP + scol;
            fr[0] = *(const f16x8*)(src);
            fr[1] = *(const f16x8*)(src + 8);
            fr[2] = *(const f16x8*)(src + 16);
            fr[3] = *(const f16x8*)(src + 24);
        }
        f16x8 hv[4][4];
        #pragma unroll
        for (int ks = 0; ks < 4; ks++)
            #pragma unroll
            for (int df = 0; df < 4; df++)
                hv[ks][df] = *(const f16x8*)(hT +
                    ((size_t)b * CC + dbase + df * 16 + ln) * NN + m0 + ks * 32 + quad * 8);

        // ---- QK^T: S[mf] = D[16q x 16m], mf = 0..7 over 128 keys ----
        f32x4 S[8];
        #pragma unroll
        for (int mf = 0; mf < 8; mf++) {
            f16x8 bf0 = *(const f16x8*)&f_s[mf * 16 + ln][quad * 8];
            f16x8 bf1 = *(const f16x8*)&f_s[mf * 16 + ln][32 + quad * 8];
            f32x4 s = {};
            s = MFMA16(ag0, bf0, s);
            s = MFMA16(ag1, bf1, s);
            S[mf] = s;
        }

        // ---- online softmax (base-2), rows q = w*16 + quad*4 + r ----
        #pragma unroll
        for (int r = 0; r < 4; r++) {
            float mx = fmaxf(fmaxf(fmaxf(S[0][r], S[1][r]), fmaxf(S[2][r], S[3][r])),
                             fmaxf(fmaxf(S[4][r], S[5][r]), fmaxf(S[6][r], S[7][r])));
            mx = max16(mx);
            float mnew = fmaxf(m_run[r], mx);
            float al   = fast_exp2(m_run[r] - mnew);
            float p[8];
            float sum = 0.f;
            #pragma unroll
            for (int mf = 0; mf < 8; mf++) {
                p[mf] = fast_exp2(S[mf][r] - mnew);
                sum += p[mf];
            }
            sum = sum16(sum);
            l_run[r] = l_run[r] * al + sum;
            m_run[r] = mnew;
            const int qrow = w * 16 + quad * 4 + r;
            if (ln == 0) alpha_s[qrow] = al;
            f16x4 pkLo = { (_Float16)p[0], (_Float16)p[1], (_Float16)p[2], (_Float16)p[3] };
            f16x4 pkHi = { (_Float16)p[4], (_Float16)p[5], (_Float16)p[6], (_Float16)p[7] };
            *(f16x4*)&p_s[qrow][ln * 4]      = pkLo;   // perm col = ln*4+mf
            *(f16x4*)&p_s[qrow][64 + ln * 4] = pkHi;
        }
        __syncthreads();   // barrier 2: p_s/alpha_s visible

        // ---- rescale (broadcast float4 reads; skip when all alphas == 1) ----
        float4 alv[4];
        bool need = false;
        #pragma unroll
        for (int qf = 0; qf < 4; qf++) {
            alv[qf] = *(const float4*)&alpha_s[qf * 16 + quad * 4];
            need |= (alv[qf].x != 1.0f) | (alv[qf].y != 1.0f) |
                    (alv[qf].z != 1.0f) | (alv[qf].w != 1.0f);
        }
        if (__ballot(need)) {
            #pragma unroll
            for (int qf = 0; qf < 4; qf++)
                #pragma unroll
                for (int df = 0; df < 4; df++) {
                    acc[qf][df][0] *= alv[qf].x;
                    acc[qf][df][1] *= alv[qf].y;
                    acc[qf][df][2] *= alv[qf].z;
                    acc[qf][df][3] *= alv[qf].w;
                }
        }

        // ---- PV: P x h^T over this wave's 64 channels, k = 128 keys ----
        #pragma unroll
        for (int ks = 0; ks < 4; ks++) {
            #pragma unroll
            for (int qf = 0; qf < 4; qf++) {
                f16x8 ap = *(const f16x8*)&p_s[qf * 16 + ln][ks * 32 + quad * 8];
                #pragma unroll
                for (int df = 0; df < 4; df++)
                    acc[qf][df] = MFMA16(ap, hv[ks][df], acc[qf][df]);
            }
        }
    }

    // ---- exchange l across waves, fused epilogue ----
    if (ln == 0) {
        #pragma unroll
        for (int r = 0; r < 4; r++) l_s[w * 16 + quad * 4 + r] = l_run[r];
    }
    __syncthreads();

    const float gam = gamma[0];
    #pragma unroll
    for (int qf = 0; qf < 4; qf++) {
        #pragma unroll
        for (int r = 0; r < 4; r++) {
            const int q = qf * 16 + quad * 4 + r;
            const float linv = 1.0f / l_s[q];
            #pragma unroll
            for (int df = 0; df < 4; df++) {
                const int d = dbase + df * 16 + ln;
                size_t idx = ((size_t)b * NN + q0 + q) * CC + d;
                out[idx] = fmaf(gam, acc[qf][df][r] * linv, inp[idx]);
            }
        }
    }
}

// ---------------------------------------------------------------------------
extern "C" void kernel_launch(void* const* d_in, const int* in_sizes, int n_in,
                              void* d_out, int out_size, void* d_ws, size_t ws_size,
                              hipStream_t stream) {
    const float* input = (const float*)d_in[0];
    const float* nms   = (const float*)d_in[1];
    const float* WF    = (const float*)d_in[2];
    const float* WG    = (const float*)d_in[3];
    const float* WH    = (const float*)d_in[4];
    const float* gamma = (const float*)d_in[5];
    float* out = (float*)d_out;

    // workspace: W16 (192 KB) | fb16 (4 MB) | gb16 (4 MB) | hT16 (16 MB)
    char* ws = (char*)d_ws;
    _Float16* W16  = (_Float16*)ws;
    _Float16* fb16 = (_Float16*)(ws + 196608);
    _Float16* gb16 = (_Float16*)(ws + 196608 + 4194304);
    _Float16* hT16 = (_Float16*)(ws + 196608 + 2 * 4194304);

    wconv_kernel<<<96, 256, 0, stream>>>(WF, WG, WH, W16);
    proj16_kernel<<<dim3(NN / 64, BB), 256, 0, stream>>>(nms, W16, fb16, gb16, hT16);
    attn16_kernel<<<dim3(BB, NN / 64), 256, 0, stream>>>(fb16, gb16, hT16, input, gamma, out);
}